// Round 14
// baseline (1549.556 us; speedup 1.0000x reference)
//
#include <hip/hip_runtime.h>
#include <math.h>
#include <float.h>

#define M_TOK   32768
#define NSYM    8192
#define KDIM    1024
#define LAT     512

#define DECAY_F 0.995f
#define OMD_F   0.005f
#define GBS_F   0.7f
#define EPS_F   1e-6f
#define WIN_F   2.5f            // 0.7 bias + 2*(8-sigma bf16 screen err ~0.9)
#define LOSS_SCALE (1.25f / 33554432.0f)

typedef unsigned short u16;
typedef unsigned int   u32;
typedef short short8 __attribute__((ext_vector_type(8)));
typedef float f32x4  __attribute__((ext_vector_type(4)));

#define GLOAD_LDS16(g, l) \
    __builtin_amdgcn_global_load_lds((const __attribute__((address_space(1))) u32*)(g), \
                                     (__attribute__((address_space(3))) u32*)(l), 16, 0, 0)

__device__ __forceinline__ u16 f2bf(float f) {
    u32 u = __float_as_uint(f);
    return (u16)((u + 0x7FFF + ((u >> 16) & 1)) >> 16);   // round-to-nearest-even
}

// ---------------- fused convert A + convert B(+cnorm) + zero ----------------
__global__ void k_conv(const float* __restrict__ zr, const float* __restrict__ zi,
                       const float* __restrict__ cb,
                       u16* __restrict__ A, u16* __restrict__ B,
                       float* __restrict__ cnorm,
                       u32* __restrict__ counts, u32* __restrict__ cursors,
                       u32* __restrict__ qcount, float* __restrict__ out_loss) {
    const int bid = blockIdx.x;
    if (bid < 16384) {
        size_t t = (size_t)bid * 256 + threadIdx.x;
        size_t base = t * 8;
        int tok = (int)(base >> 10);
        int k0  = (int)(base & 1023);
        const float* src = (k0 < 512) ? zr + (size_t)tok * 512 + k0
                                      : zi + (size_t)tok * 512 + (k0 - 512);
        float4 f0 = *(const float4*)src;
        float4 f1 = *(const float4*)(src + 4);
        u32 q0 = f2bf(f0.x) | ((u32)f2bf(f0.y) << 16);
        u32 q1 = f2bf(f0.z) | ((u32)f2bf(f0.w) << 16);
        u32 q2 = f2bf(f1.x) | ((u32)f2bf(f1.y) << 16);
        u32 q3 = f2bf(f1.z) | ((u32)f2bf(f1.w) << 16);
        *(uint4*)&A[base] = make_uint4(q0, q1, q2, q3);
    } else if (bid < 20480) {
        const int b2 = bid - 16384;
        size_t t = (size_t)b2 * 256 + threadIdx.x;
        size_t base = t * 8;
        float4 f0 = *(const float4*)&cb[base];
        float4 f1 = *(const float4*)&cb[base + 4];
        u32 q0 = f2bf(f0.x) | ((u32)f2bf(f0.y) << 16);
        u32 q1 = f2bf(f0.z) | ((u32)f2bf(f0.w) << 16);
        u32 q2 = f2bf(f1.x) | ((u32)f2bf(f1.y) << 16);
        u32 q3 = f2bf(f1.z) | ((u32)f2bf(f1.w) << 16);
        *(uint4*)&B[base] = make_uint4(q0, q1, q2, q3);
        float nrm = f0.x * f0.x + f0.y * f0.y + f0.z * f0.z + f0.w * f0.w
                  + f1.x * f1.x + f1.y * f1.y + f1.z * f1.z + f1.w * f1.w;
#pragma unroll
        for (int m = 32; m; m >>= 1) nrm += __shfl_xor(nrm, m, 64);
        __shared__ float part[4];
        int lane = threadIdx.x & 63, w = threadIdx.x >> 6;
        if (lane == 0) part[w] = nrm;
        __syncthreads();
        if (threadIdx.x == 0)   cnorm[b2 * 2]     = part[0] + part[1];
        if (threadIdx.x == 128) cnorm[b2 * 2 + 1] = part[2] + part[3];
    } else {
        int i = (bid - 20480) * 256 + threadIdx.x;
        if (i < NSYM) { counts[i] = 0; cursors[i] = 0; }
        if (i == 0) { qcount[0] = 0; out_loss[0] = 0.0f; }
    }
}

// ---------------- bf16 MFMA screen: 3-ring counted-vmcnt pipeline (T4) ----------------
// grid 1024 (XCD-swizzled). BK=32, 512 K-steps total (16 chunks x 32 steps).
// Per step: vmcnt(4) -> raw barrier -> issue prefetch(g+2) -> ds_read -> 16 MFMA.
__global__ __launch_bounds__(256) void k_screen(
    const u16* __restrict__ Ah, const u16* __restrict__ Bh,
    const float* __restrict__ cnorm,
    float* __restrict__ candV, u16* __restrict__ candI)
{
    __shared__ __align__(16) unsigned char ringA[3][8192];   // [128 rows][32 k] bf16 each
    __shared__ __align__(16) unsigned char ringB[3][8192];
    __shared__ float smv[128][2][2];
    __shared__ float smi[128][2];

    const int sblk = (blockIdx.x & 7) * 128 + (blockIdx.x >> 3);
    const int bx = sblk >> 2;
    const int by = sblk & 3;

    const int tid  = threadIdx.x;
    const int lane = tid & 63;
    const int w    = tid >> 6;
    const int wr   = w >> 1, wc = w & 1;
    const int row0 = bx * 128;

    // stage global K-step g into ring slot ri (4 gloads/thread, wave-uniform LDS base)
    auto stage = [&](int g, int ri) {
        const int chunk = by * 16 + (g >> 5);
        const int kk0 = (g & 31) * 32;
#pragma unroll
        for (int i = 0; i < 2; ++i) {
            int slotBase = i * 256 + w * 64;
            int slot = slotBase + lane;
            int r = slot >> 2;
            int c = (slot & 3) ^ (r & 3);
            const u16* ga = Ah + (((size_t)(row0 + r)) << 10) + kk0 + c * 8;
            GLOAD_LDS16(ga, ringA[ri] + slotBase * 16);
            const u16* gb = Bh + (((size_t)(chunk * 128 + r)) << 10) + kk0 + c * 8;
            GLOAD_LDS16(gb, ringB[ri] + slotBase * 16);
        }
    };

    stage(0, 0);
    stage(1, 1);
    int bi = 0;

    for (int cc = 0; cc < 16; ++cc) {
        f32x4 acc[4][4];
#pragma unroll
        for (int m = 0; m < 4; ++m)
#pragma unroll
            for (int n = 0; n < 4; ++n) acc[m][n] = (f32x4){0.f, 0.f, 0.f, 0.f};

        for (int ks = 0; ks < 32; ++ks) {
            const int g = cc * 32 + ks;
            // own step-g loads landed (others' via barrier); 4 newest (g+1) may fly
            asm volatile("s_waitcnt vmcnt(4)" ::: "memory");
            __builtin_amdgcn_s_barrier();
            if (g + 2 < 512) {
                int bi2 = bi + 2; if (bi2 >= 3) bi2 -= 3;
                stage(g + 2, bi2);
            }
            short8 af[4], bfr[4];
#pragma unroll
            for (int m = 0; m < 4; ++m) {
                int r = wr * 64 + m * 16 + (lane & 15);
                int gg = (lane >> 4) ^ (r & 3);
                af[m] = *(const short8*)(ringA[bi] + r * 64 + gg * 16);
            }
#pragma unroll
            for (int n = 0; n < 4; ++n) {
                int r = wc * 64 + n * 16 + (lane & 15);
                int gg = (lane >> 4) ^ (r & 3);
                bfr[n] = *(const short8*)(ringB[bi] + r * 64 + gg * 16);
            }
#pragma unroll
            for (int m = 0; m < 4; ++m)
#pragma unroll
                for (int n = 0; n < 4; ++n)
                    acc[m][n] = __builtin_amdgcn_mfma_f32_16x16x32_bf16(
                        af[m], bfr[n], acc[m][n], 0, 0, 0);
            ++bi; if (bi == 3) bi = 0;
        }

        // epilogue (identical logic to r13): per-HALF top-2 + best idx
        const int chunk = by * 16 + cc;
        const int colBase = chunk * 128;
        float cn[4];
#pragma unroll
        for (int n = 0; n < 4; ++n)
            cn[n] = cnorm[colBase + wc * 64 + n * 16 + (lane & 15)];

#pragma unroll
        for (int m = 0; m < 4; ++m)
#pragma unroll
            for (int j = 0; j < 4; ++j) {
                int rowL = wr * 64 + m * 16 + (lane >> 4) * 4 + j;
                float v1 = INFINITY, v2 = INFINITY, i1v = 0.f;
#pragma unroll
                for (int n = 0; n < 4; ++n) {
                    float s = cn[n] - 2.0f * acc[m][n][j];
                    float ci = (float)(colBase + wc * 64 + n * 16 + (lane & 15));
                    if (s < v1) { v2 = v1; v1 = s; i1v = ci; }
                    else v2 = fminf(v2, s);
                }
#pragma unroll
                for (int msk = 1; msk < 16; msk <<= 1) {
                    float o1 = __shfl_xor(v1, msk, 16);
                    float oi = __shfl_xor(i1v, msk, 16);
                    float o2 = __shfl_xor(v2, msk, 16);
                    float n2 = fminf(fminf(v2, o2), fmaxf(v1, o1));
                    if (o1 < v1) { v1 = o1; i1v = oi; }
                    v2 = n2;
                }
                if ((lane & 15) == 0) {
                    smv[rowL][wc][0] = v1;  smv[rowL][wc][1] = v2;
                    smi[rowL][wc] = i1v;
                }
            }
        __syncthreads();
        {
            int half = tid >> 7;
            int row  = tid & 127;
            float v1 = smv[row][half][0], v2 = smv[row][half][1];
            float iv = smi[row][half];
            size_t tcol = (size_t)(row0 + row);
            int halfIdx = chunk * 2 + half;
            candV[(size_t)(halfIdx * 2 + 0) * M_TOK + tcol] = v1;
            candV[(size_t)(halfIdx * 2 + 1) * M_TOK + tcol] = v2;
            candI[(size_t)halfIdx * M_TOK + tcol]           = (u16)iv;
        }
        __syncthreads();   // smv/smi safe for reuse next chunk
    }
}

// ---------------- zero (fallback path only, after screen) ----------------
__global__ void k_zero(u32* __restrict__ counts, u32* __restrict__ cursors,
                       u32* __restrict__ qcount, float* __restrict__ out_loss) {
    int i = blockIdx.x * 256 + threadIdx.x;
    if (i < NSYM) { counts[i] = 0; cursors[i] = 0; }
    if (i == 0) { out_loss[0] = 0.0f; qcount[0] = 0; }
}

// ---------------- fp64 rescore helper ----------------
__device__ __forceinline__ void rescore(
    const float* __restrict__ codebook, const float* __restrict__ adjacency,
    const double* zreg, int prw, int col, int lane, double& bestS, int& bestI)
{
    const float* crow = codebook + (size_t)col * KDIM;
    double dot = 0.0, cn2 = 0.0;
#pragma unroll
    for (int j = 0; j < 16; ++j) {
        double c = (double)crow[lane + 64 * j];
        dot += c * zreg[j]; cn2 += c * c;
    }
#pragma unroll
    for (int m = 32; m; m >>= 1) {
        dot += __shfl_xor(dot, m, 64);
        cn2 += __shfl_xor(cn2, m, 64);
    }
    double a = (double)adjacency[(size_t)prw * NSYM + col];
    double sc = cn2 - 2.0 * dot - (double)GBS_F / (1.0 + exp(-a));
    if (sc < bestS || (sc == bestS && col < bestI)) { bestS = sc; bestI = col; }
}

// ---------------- select: inline singles; queue only scan-needing tokens ----------------
#define SEL_TOK 32
__global__ __launch_bounds__(256) void k_select(
    const float* __restrict__ zr, const float* __restrict__ zi,
    const int* __restrict__ prev,
    const float* __restrict__ codebook,
    const float* __restrict__ adjacency,
    const float* __restrict__ candV, const u16* __restrict__ candI,
    float* __restrict__ out_idx, u32* __restrict__ counts,
    u32* __restrict__ qcount, u32* __restrict__ queue)
{
    __shared__ float sv[256][SEL_TOK + 1];
    __shared__ u16   si[128][SEL_TOK + 2];
    const int tok0 = blockIdx.x * SEL_TOK;
    const int w = threadIdx.x >> 6, lane = threadIdx.x & 63;

    for (int idx = threadIdx.x; idx < 256 * SEL_TOK; idx += 256) {
        int e = idx >> 5, t = idx & (SEL_TOK - 1);
        sv[e][t] = candV[(size_t)e * M_TOK + tok0 + t];
    }
    for (int idx = threadIdx.x; idx < 128 * SEL_TOK; idx += 256) {
        int e = idx >> 5, t = idx & (SEL_TOK - 1);
        si[e][t] = candI[(size_t)e * M_TOK + tok0 + t];
    }
    __syncthreads();

    for (int tt = 0; tt < SEL_TOK / 4; ++tt) {
        const int t = w * (SEL_TOK / 4) + tt;
        const int tok = tok0 + t;
        float va1 = sv[4 * lane + 0][t];
        float va2 = sv[4 * lane + 1][t];
        float vb1 = sv[4 * lane + 2][t];
        float vb2 = sv[4 * lane + 3][t];
        int   ia  = (int)si[2 * lane + 0][t];
        int   ib  = (int)si[2 * lane + 1][t];

        float mm = fminf(va1, vb1);
#pragma unroll
        for (int m = 32; m; m >>= 1) mm = fminf(mm, __shfl_xor(mm, m, 64));
        const float thr = mm + WIN_F;

        unsigned long long m1a = __ballot(va1 <= thr);
        unsigned long long m1b = __ballot(vb1 <= thr);
        unsigned long long mh  = __ballot(va2 <= thr) | __ballot(vb2 <= thr);

        if (mh != 0) {
            if (lane == 0) { u32 q = atomicAdd(qcount, 1u); queue[q] = (u32)tok; }
        } else if (__popcll(m1a) + __popcll(m1b) == 1) {
            int bestI;
            if (m1a) { int c = __ffsll(m1a) - 1; bestI = __shfl(ia, c, 64); }
            else     { int c = __ffsll(m1b) - 1; bestI = __shfl(ib, c, 64); }
            if (lane == 0) {
                out_idx[tok] = (float)bestI;
                atomicAdd(&counts[bestI], 1u);
            }
        } else {
            double zreg[16];
#pragma unroll
            for (int j = 0; j < 8; ++j)
                zreg[j] = (double)zr[(size_t)tok * LAT + lane + 64 * j];
#pragma unroll
            for (int j = 0; j < 8; ++j)
                zreg[8 + j] = (double)zi[(size_t)tok * LAT + lane + 64 * j];
            const int prw = prev[tok];
            double bestS = DBL_MAX; int bestI = 0x7FFFFFFF;
            unsigned long long sa = m1a, sb = m1b;
            while (sa) { int c = __ffsll(sa) - 1; sa &= sa - 1;
                rescore(codebook, adjacency, zreg, prw, __shfl(ia, c, 64), lane, bestS, bestI); }
            while (sb) { int c = __ffsll(sb) - 1; sb &= sb - 1;
                rescore(codebook, adjacency, zreg, prw, __shfl(ib, c, 64), lane, bestS, bestI); }
            if (lane == 0) {
                out_idx[tok] = (float)bestI;
                atomicAdd(&counts[bestI], 1u);
            }
        }
    }
}

// ---------------- rescan: block per queued token, 4-wave-parallel candidate scan ----------------
#define MAXC 384
__global__ __launch_bounds__(256) void k_rescan(
    const float* __restrict__ zr, const float* __restrict__ zi,
    const int* __restrict__ prev,
    const float* __restrict__ codebook,
    const float* __restrict__ adjacency,
    const float* __restrict__ candV, const u16* __restrict__ candI,
    const u32* __restrict__ qcount, const u32* __restrict__ queue,
    float* __restrict__ out_idx, u32* __restrict__ counts)
{
    __shared__ double zd[KDIM];
    __shared__ float v1h[128], v2h[128];
    __shared__ u16   i1h[128];
    __shared__ int   collist[MAXC];
    __shared__ int   nsing_sh, nh_sh, scanall_sh;
    __shared__ int   halves[128];
    __shared__ double wsc[4];
    __shared__ int    wix[4];
    __shared__ float  mm_sh;

    const int tid = threadIdx.x;
    const int w = tid >> 6, lane = tid & 63;
    const u32 nq = qcount[0];

    for (u32 qi = blockIdx.x; qi < nq; qi += gridDim.x) {
        const int tok = (int)queue[qi];

        if (tid < 128) {
            v1h[tid] = candV[(size_t)(tid * 2 + 0) * M_TOK + tok];
            v2h[tid] = candV[(size_t)(tid * 2 + 1) * M_TOK + tok];
            i1h[tid] = candI[(size_t)tid * M_TOK + tok];
        }
        for (int k = tid; k < LAT; k += 256) {
            zd[k]       = (double)zr[(size_t)tok * LAT + k];
            zd[LAT + k] = (double)zi[(size_t)tok * LAT + k];
        }
        if (tid == 0) { nsing_sh = 0; nh_sh = 0; scanall_sh = 0; }
        __syncthreads();

        if (tid < 64) {
            float m = fminf(v1h[tid], v1h[tid + 64]);
#pragma unroll
            for (int s = 32; s; s >>= 1) m = fminf(m, __shfl_xor(m, s, 64));
            if (tid == 0) mm_sh = m;
        }
        __syncthreads();
        const float thr = mm_sh + WIN_F;

        if (tid < 128) {
            bool hs = (v2h[tid] <= thr);
            if (hs) { int p = atomicAdd(&nh_sh, 1); halves[p] = tid; }
            else if (v1h[tid] <= thr) { int p = atomicAdd(&nsing_sh, 1); collist[p] = (int)i1h[tid]; }
        }
        __syncthreads();
        int nsing = nsing_sh, nh = nh_sh;
        int nc = nsing + nh * 64;
        if (nc > MAXC) { if (tid == 0) scanall_sh = 1; }
        __syncthreads();
        if (!scanall_sh) {
            for (int h = 0; h < nh; ++h) {
                if (tid < 64) collist[nsing + h * 64 + tid] = halves[h] * 64 + tid;
            }
            nc = nsing + nh * 64;
        }
        __syncthreads();

        const int prw = prev[tok];
        double bestS = DBL_MAX; int bestI = 0x7FFFFFFF;
        const int total = scanall_sh ? NSYM : nc;
        for (int ci = w; ci < total; ci += 4) {
            int col = scanall_sh ? ci : collist[ci];
            const float* crow = codebook + (size_t)col * KDIM;
            double dot = 0.0, cn2 = 0.0;
#pragma unroll
            for (int j = 0; j < 16; ++j) {
                double c = (double)crow[lane + 64 * j];
                dot += c * zd[lane + 64 * j]; cn2 += c * c;
            }
#pragma unroll
            for (int s = 32; s; s >>= 1) {
                dot += __shfl_xor(dot, s, 64);
                cn2 += __shfl_xor(cn2, s, 64);
            }
            double a = (double)adjacency[(size_t)prw * NSYM + col];
            double sc = cn2 - 2.0 * dot - (double)GBS_F / (1.0 + exp(-a));
            if (sc < bestS || (sc == bestS && col < bestI)) { bestS = sc; bestI = col; }
        }
        if (lane == 0) { wsc[w] = bestS; wix[w] = bestI; }
        __syncthreads();
        if (tid == 0) {
            double bs = wsc[0]; int bi = wix[0];
#pragma unroll
            for (int q = 1; q < 4; ++q) {
                if (wsc[q] < bs || (wsc[q] == bs && wix[q] < bi)) { bs = wsc[q]; bi = wix[q]; }
            }
            out_idx[tok] = (float)bi;
            atomicAdd(&counts[bi], 1u);
        }
        __syncthreads();
    }
}

// ---------------- scan: offsets, new_cluster_size, n_total ----------------
__global__ __launch_bounds__(1024) void k_scan(
    const u32* __restrict__ counts, const float* __restrict__ cs_old,
    float* __restrict__ out_cs, u32* __restrict__ offsets,
    float* __restrict__ scal)
{
    const int tid = threadIdx.x;
    const int lane = tid & 63, w = tid >> 6;
    const int base = tid * 8;
    u32 c[8], pre[8], T = 0;
#pragma unroll
    for (int q = 0; q < 8; ++q) { c[q] = counts[base + q]; pre[q] = T; T += c[q]; }
    u32 inc = T;
#pragma unroll
    for (int d = 1; d < 64; d <<= 1) {
        u32 v = __shfl_up(inc, d, 64);
        if (lane >= d) inc += v;
    }
    __shared__ u32 wt[16];
    if (lane == 63) wt[w] = inc;
    __syncthreads();
    if (tid < 16) {
        u32 v = wt[tid];
#pragma unroll
        for (int d = 1; d < 16; d <<= 1) {
            u32 o = __shfl_up(v, d, 16);
            if (tid >= d) v += o;
        }
        wt[tid] = v;
    }
    __syncthreads();
    u32 ex = (w ? wt[w - 1] : 0) + inc - T;
#pragma unroll
    for (int q = 0; q < 8; ++q) offsets[base + q] = ex + pre[q];

    float nt = 0.0f;
#pragma unroll
    for (int q = 0; q < 8; ++q) {
        float ncs = cs_old[base + q] * DECAY_F + OMD_F * (float)c[q];
        out_cs[base + q] = ncs;
        nt += ncs;
    }
#pragma unroll
    for (int m = 32; m; m >>= 1) nt += __shfl_xor(nt, m, 64);
    __shared__ float red[16];
    if (lane == 0) red[w] = nt;
    __syncthreads();
    if (tid == 0) {
        float s = 0.0f;
#pragma unroll
        for (int i = 0; i < 16; ++i) s += red[i];
        scal[0] = s;
        scal[1] = s + (float)NSYM * EPS_F;
    }
}

// ---------------- place: token lists per symbol ----------------
__global__ void k_place(const float* __restrict__ idxf, const u32* __restrict__ offsets,
                        u32* __restrict__ cursors, u32* __restrict__ list) {
    int t = blockIdx.x * 256 + threadIdx.x;
    int s = (int)idxf[t];
    u32 slot = atomicAdd(&cursors[s], 1u);
    list[offsets[s] + slot] = (u32)t;
}

// ---------------- emit FUSED with zq, 2-token-parallel (ws path) ----------------
__global__ __launch_bounds__(256) void k_emit_fused(
    const float* __restrict__ zr, const float* __restrict__ zi,
    const float* __restrict__ codebook, const float* __restrict__ embed_avg,
    const u32* __restrict__ counts, const u32* __restrict__ offsets,
    const u32* __restrict__ list, const float* __restrict__ out_cs,
    const float* __restrict__ scal,
    float* __restrict__ out_ea, float* __restrict__ out_cb,
    float* __restrict__ out_zc, float* __restrict__ out_loss, int interleaved)
{
    const int s = blockIdx.x;
    const u32 cnt = counts[s], off = offsets[s];
    const int g = threadIdx.x >> 7;          // token group 0/1
    const int j = (threadIdx.x & 127) * 4;   // column quad
    float4 cbr = *(const float4*)&codebook[(size_t)s * KDIM + j];
    float4 cbi = *(const float4*)&codebook[(size_t)s * KDIM + LAT + j];
    float ar0 = 0.f, ar1 = 0.f, ar2 = 0.f, ar3 = 0.f;
    float ai0 = 0.f, ai1 = 0.f, ai2 = 0.f, ai3 = 0.f;
    float lsum = 0.f;
    for (u32 n = g; n < cnt; n += 2) {
        int t = (int)list[off + n];
        float4 z0 = *(const float4*)&zr[(size_t)t * LAT + j];
        float4 z1 = *(const float4*)&zi[(size_t)t * LAT + j];
        ar0 += z0.x; ar1 += z0.y; ar2 += z0.z; ar3 += z0.w;
        ai0 += z1.x; ai1 += z1.y; ai2 += z1.z; ai3 += z1.w;
        if (interleaved) {
            float2* dst = (float2*)out_zc + (size_t)t * LAT + j;
            dst[0] = make_float2(cbr.x, cbi.x); dst[1] = make_float2(cbr.y, cbi.y);
            dst[2] = make_float2(cbr.z, cbi.z); dst[3] = make_float2(cbr.w, cbi.w);
        } else {
            *(float4*)&out_zc[(size_t)t * LAT + j] = cbr;
        }
        float d;
        d = cbr.x - z0.x; lsum += d * d;  d = cbr.y - z0.y; lsum += d * d;
        d = cbr.z - z0.z; lsum += d * d;  d = cbr.w - z0.w; lsum += d * d;
        d = cbi.x - z1.x; lsum += d * d;  d = cbi.y - z1.y; lsum += d * d;
        d = cbi.z - z1.z; lsum += d * d;  d = cbi.w - z1.w; lsum += d * d;
    }
    __shared__ float comb[128][8];
    if (g == 1) {
        int r = threadIdx.x & 127;
        comb[r][0] = ar0; comb[r][1] = ar1; comb[r][2] = ar2; comb[r][3] = ar3;
        comb[r][4] = ai0; comb[r][5] = ai1; comb[r][6] = ai2; comb[r][7] = ai3;
    }
    __syncthreads();
    if (g == 0) {
        int r = threadIdx.x;
        ar0 += comb[r][0]; ar1 += comb[r][1]; ar2 += comb[r][2]; ar3 += comb[r][3];
        ai0 += comb[r][4]; ai1 += comb[r][5]; ai2 += comb[r][6]; ai3 += comb[r][7];
        float4 ea0 = *(const float4*)&embed_avg[(size_t)s * KDIM + j];
        float4 ea1 = *(const float4*)&embed_avg[(size_t)s * KDIM + LAT + j];
        float4 ner = make_float4(ea0.x * DECAY_F + ar0 * OMD_F, ea0.y * DECAY_F + ar1 * OMD_F,
                                 ea0.z * DECAY_F + ar2 * OMD_F, ea0.w * DECAY_F + ar3 * OMD_F);
        float4 nei = make_float4(ea1.x * DECAY_F + ai0 * OMD_F, ea1.y * DECAY_F + ai1 * OMD_F,
                                 ea1.z * DECAY_F + ai2 * OMD_F, ea1.w * DECAY_F + ai3 * OMD_F);
        *(float4*)&out_ea[(size_t)s * KDIM + j]       = ner;
        *(float4*)&out_ea[(size_t)s * KDIM + LAT + j] = nei;
        float ntot = scal[0], denom = scal[1];
        float cs = (out_cs[s] + EPS_F) / denom * ntot;
        float inv = 1.0f / cs;
        *(float4*)&out_cb[(size_t)s * KDIM + j] =
            make_float4(ner.x * inv, ner.y * inv, ner.z * inv, ner.w * inv);
        *(float4*)&out_cb[(size_t)s * KDIM + LAT + j] =
            make_float4(nei.x * inv, nei.y * inv, nei.z * inv, nei.w * inv);
    }
#pragma unroll
    for (int m = 32; m; m >>= 1) lsum += __shfl_xor(lsum, m, 64);
    __shared__ float red[4];
    int wv = threadIdx.x >> 6, lane = threadIdx.x & 63;
    if (lane == 0) red[wv] = lsum;
    __syncthreads();
    if (threadIdx.x == 0)
        atomicAdd(out_loss, (red[0] + red[1] + red[2] + red[3]) * LOSS_SCALE);
}

// ---------------- emit (fallback, unfused) ----------------
__global__ __launch_bounds__(256) void k_emit(
    const float* __restrict__ zr, const float* __restrict__ zi,
    const float* __restrict__ embed_avg,
    const u32* __restrict__ counts, const u32* __restrict__ offsets,
    const u32* __restrict__ list, const float* __restrict__ out_cs,
    const float* __restrict__ scal,
    float* __restrict__ out_ea, float* __restrict__ out_cb)
{
    const int s = blockIdx.x;
    const u32 cnt = counts[s], off = offsets[s];
    const int j = threadIdx.x * 4;
    float a0 = 0.f, a1 = 0.f, a2 = 0.f, a3 = 0.f;
    for (u32 n = 0; n < cnt; ++n) {
        int t = (int)list[off + n];
        const float* src = (j < 512) ? zr + (size_t)t * 512 + j
                                     : zi + (size_t)t * 512 + (j - 512);
        float4 v = *(const float4*)src;
        a0 += v.x; a1 += v.y; a2 += v.z; a3 += v.w;
    }
    float4 ea = *(const float4*)&embed_avg[(size_t)s * KDIM + j];
    float4 nea = make_float4(ea.x * DECAY_F + a0 * OMD_F,
                             ea.y * DECAY_F + a1 * OMD_F,
                             ea.z * DECAY_F + a2 * OMD_F,
                             ea.w * DECAY_F + a3 * OMD_F);
    *(float4*)&out_ea[(size_t)s * KDIM + j] = nea;
    float ntot = scal[0], denom = scal[1];
    float cs = (out_cs[s] + EPS_F) / denom * ntot;
    float inv = 1.0f / cs;
    *(float4*)&out_cb[(size_t)s * KDIM + j] =
        make_float4(nea.x * inv, nea.y * inv, nea.z * inv, nea.w * inv);
}

// ---------------- zq (fallback, unfused; loss pre-scaled) ----------------
__global__ __launch_bounds__(256) void k_zq(
    const float* __restrict__ zr, const float* __restrict__ zi,
    const float* __restrict__ codebook, const float* __restrict__ idxf,
    float* __restrict__ out_zc, float* __restrict__ out_loss, int interleaved)
{
    const int w = threadIdx.x >> 6, lane = threadIdx.x & 63;
    const int tok = blockIdx.x * 4 + w;
    const int mi = (int)idxf[tok];
    const int j0 = lane * 8;
    float4 re0 = *(const float4*)&codebook[(size_t)mi * KDIM + j0];
    float4 re1 = *(const float4*)&codebook[(size_t)mi * KDIM + j0 + 4];
    float4 im0 = *(const float4*)&codebook[(size_t)mi * KDIM + LAT + j0];
    float4 im1 = *(const float4*)&codebook[(size_t)mi * KDIM + LAT + j0 + 4];
    float4 zr0 = *(const float4*)&zr[(size_t)tok * LAT + j0];
    float4 zr1 = *(const float4*)&zr[(size_t)tok * LAT + j0 + 4];
    float4 zi0 = *(const float4*)&zi[(size_t)tok * LAT + j0];
    float4 zi1 = *(const float4*)&zi[(size_t)tok * LAT + j0 + 4];
    if (interleaved) {
        float2* dst = (float2*)out_zc + (size_t)tok * LAT + j0;
        dst[0] = make_float2(re0.x, im0.x); dst[1] = make_float2(re0.y, im0.y);
        dst[2] = make_float2(re0.z, im0.z); dst[3] = make_float2(re0.w, im0.w);
        dst[4] = make_float2(re1.x, im1.x); dst[5] = make_float2(re1.y, im1.y);
        dst[6] = make_float2(re1.z, im1.z); dst[7] = make_float2(re1.w, im1.w);
    } else {
        *(float4*)&out_zc[(size_t)tok * LAT + j0]     = re0;
        *(float4*)&out_zc[(size_t)tok * LAT + j0 + 4] = re1;
    }
    float l = 0.f;
    l += (re0.x-zr0.x)*(re0.x-zr0.x) + (re0.y-zr0.y)*(re0.y-zr0.y)
       + (re0.z-zr0.z)*(re0.z-zr0.z) + (re0.w-zr0.w)*(re0.w-zr0.w);
    l += (re1.x-zr1.x)*(re1.x-zr1.x) + (re1.y-zr1.y)*(re1.y-zr1.y)
       + (re1.z-zr1.z)*(re1.z-zr1.z) + (re1.w-zr1.w)*(re1.w-zr1.w);
    l += (im0.x-zi0.x)*(im0.x-zi0.x) + (im0.y-zi0.y)*(im0.y-zi0.y)
       + (im0.z-zi0.z)*(im0.z-zi0.z) + (im0.w-zi0.w)*(im0.w-zi0.w);
    l += (im1.x-zi1.x)*(im1.x-zi1.x) + (im1.y-zi1.y)*(im1.y-zi1.y)
       + (im1.z-zi1.z)*(im1.z-zi1.z) + (im1.w-zi1.w)*(im1.w-zi1.w);
#pragma unroll
    for (int m = 32; m; m >>= 1) l += __shfl_xor(l, m, 64);
    if (lane == 0) atomicAdd(out_loss, l * LOSS_SCALE);
}

extern "C" void kernel_launch(void* const* d_in, const int* in_sizes, int n_in,
                              void* d_out, int out_size, void* d_ws, size_t ws_size,
                              hipStream_t stream) {
    const float* z_real     = (const float*)d_in[0];
    const float* z_imag     = (const float*)d_in[1];
    const int*   prev_idx   = (const int*)d_in[2];
    const float* codebook   = (const float*)d_in[3];
    const float* cluster_sz = (const float*)d_in[4];
    const float* embed_avg  = (const float*)d_in[5];
    const float* adjacency  = (const float*)d_in[6];

    float* out = (float*)d_out;

    const size_t REST = 1 + (size_t)M_TOK + (size_t)NSYM * KDIM + NSYM
                      + (size_t)NSYM * KDIM;               // 16,818,177
    size_t zc_n = (size_t)out_size - REST;
    const size_t n_z = (size_t)M_TOK * LAT;
    int interleaved = (zc_n >= 2 * n_z) ? 1 : 0;

    float* out_zc   = out;
    float* out_loss = out + zc_n;
    float* out_idx  = out + zc_n + 1;
    float* out_cb   = out + zc_n + 1 + M_TOK;
    float* out_cs   = out_cb + (size_t)NSYM * KDIM;
    float* out_ea   = out_cs + NSYM;

    // phase-1 scratch (screen inputs), carved from output regions:
    u16*   A_hi  = (u16*)out_zc;                       // 67.1 MB (zc region)
    u16*   B_hi  = (u16*)out_cb;                       // 16.8 MB (cb region)
    float* cnorm = out_cb + 4194304;                   // 32 KB after B_hi
    float* candV = out_ea;                             // 33.5 MB [256][M]
    u16*   candI = (u16*)(out_cb + 4202496);           // 8.4 MB  [128][M]

    // phase-2 scratch: prefer d_ws (enables fused emit+zq); fallback to zc region
    const size_t WS_NEED = (size_t)(NSYM * 3 + M_TOK * 2 + 8) * 4;  // ~360 KB
    int use_ws = (ws_size >= WS_NEED) ? 1 : 0;
    u32 *counts, *cursors, *offsets, *list, *qcount, *queue;
    float* scal;
    if (use_ws) {
        u32* wsp = (u32*)d_ws;
        counts  = wsp;             cursors = counts + NSYM;
        offsets = cursors + NSYM;  list    = offsets + NSYM;
        queue   = list + M_TOK;
        scal    = (float*)(queue + M_TOK);
        qcount  = (u32*)(scal + 2);
    } else {
        counts  = (u32*)out_zc;    cursors = counts + NSYM;
        offsets = cursors + NSYM;  list    = offsets + NSYM;
        scal    = (float*)(list + M_TOK);
        qcount  = (u32*)(scal + 2);
        queue   = qcount + 1;
    }

    k_conv<<<use_ws ? 20512 : 20480, 256, 0, stream>>>(z_real, z_imag, codebook,
                                                       A_hi, B_hi, cnorm,
                                                       counts, cursors, qcount,
                                                       out_loss);
    k_screen<<<1024, 256, 0, stream>>>(A_hi, B_hi, cnorm, candV, candI);
    if (!use_ws)
        k_zero<<<32, 256, 0, stream>>>(counts, cursors, qcount, out_loss);
    k_select<<<M_TOK / SEL_TOK, 256, 0, stream>>>(z_real, z_imag, prev_idx,
                                                  codebook, adjacency,
                                                  candV, candI, out_idx, counts,
                                                  qcount, queue);
    k_rescan<<<256, 256, 0, stream>>>(z_real, z_imag, prev_idx, codebook,
                                      adjacency, candV, candI,
                                      qcount, queue, out_idx, counts);
    k_scan<<<1, 1024, 0, stream>>>(counts, cluster_sz, out_cs, offsets, scal);
    k_place<<<M_TOK / 256, 256, 0, stream>>>(out_idx, offsets, cursors, list);
    if (use_ws) {
        k_emit_fused<<<NSYM, 256, 0, stream>>>(z_real, z_imag, codebook, embed_avg,
                                               counts, offsets, list, out_cs, scal,
                                               out_ea, out_cb, out_zc, out_loss,
                                               interleaved);
    } else {
        k_emit<<<NSYM, 256, 0, stream>>>(z_real, z_imag, embed_avg, counts, offsets,
                                         list, out_cs, scal, out_ea, out_cb);
        k_zq<<<M_TOK / 4, 256, 0, stream>>>(z_real, z_imag, codebook, out_idx,
                                            out_zc, out_loss, interleaved);
    }
}

// Round 15
// 1199.855 us; speedup vs baseline: 1.2915x; 1.2915x over previous
//
#include <hip/hip_runtime.h>
#include <math.h>
#include <float.h>

#define M_TOK   32768
#define NSYM    8192
#define KDIM    1024
#define LAT     512

#define DECAY_F 0.995f
#define OMD_F   0.005f
#define GBS_F   0.7f
#define EPS_F   1e-6f
#define WIN_F   2.5f            // 0.7 bias + 2*(8-sigma bf16 screen err ~0.9)
#define LOSS_SCALE (1.25f / 33554432.0f)

typedef unsigned short u16;
typedef unsigned int   u32;
typedef short short8 __attribute__((ext_vector_type(8)));
typedef float f32x4  __attribute__((ext_vector_type(4)));

#define GLOAD_LDS16(g, l) \
    __builtin_amdgcn_global_load_lds((const __attribute__((address_space(1))) u32*)(g), \
                                     (__attribute__((address_space(3))) u32*)(l), 16, 0, 0)

__device__ __forceinline__ u16 f2bf(float f) {
    u32 u = __float_as_uint(f);
    return (u16)((u + 0x7FFF + ((u >> 16) & 1)) >> 16);   // round-to-nearest-even
}

// ---------------- fused convert A + convert B(+cnorm) + zero ----------------
__global__ void k_conv(const float* __restrict__ zr, const float* __restrict__ zi,
                       const float* __restrict__ cb,
                       u16* __restrict__ A, u16* __restrict__ B,
                       float* __restrict__ cnorm,
                       u32* __restrict__ counts, u32* __restrict__ cursors,
                       u32* __restrict__ qcount, float* __restrict__ out_loss) {
    const int bid = blockIdx.x;
    if (bid < 16384) {
        size_t t = (size_t)bid * 256 + threadIdx.x;
        size_t base = t * 8;
        int tok = (int)(base >> 10);
        int k0  = (int)(base & 1023);
        const float* src = (k0 < 512) ? zr + (size_t)tok * 512 + k0
                                      : zi + (size_t)tok * 512 + (k0 - 512);
        float4 f0 = *(const float4*)src;
        float4 f1 = *(const float4*)(src + 4);
        u32 q0 = f2bf(f0.x) | ((u32)f2bf(f0.y) << 16);
        u32 q1 = f2bf(f0.z) | ((u32)f2bf(f0.w) << 16);
        u32 q2 = f2bf(f1.x) | ((u32)f2bf(f1.y) << 16);
        u32 q3 = f2bf(f1.z) | ((u32)f2bf(f1.w) << 16);
        *(uint4*)&A[base] = make_uint4(q0, q1, q2, q3);
    } else if (bid < 20480) {
        const int b2 = bid - 16384;
        size_t t = (size_t)b2 * 256 + threadIdx.x;
        size_t base = t * 8;
        float4 f0 = *(const float4*)&cb[base];
        float4 f1 = *(const float4*)&cb[base + 4];
        u32 q0 = f2bf(f0.x) | ((u32)f2bf(f0.y) << 16);
        u32 q1 = f2bf(f0.z) | ((u32)f2bf(f0.w) << 16);
        u32 q2 = f2bf(f1.x) | ((u32)f2bf(f1.y) << 16);
        u32 q3 = f2bf(f1.z) | ((u32)f2bf(f1.w) << 16);
        *(uint4*)&B[base] = make_uint4(q0, q1, q2, q3);
        float nrm = f0.x * f0.x + f0.y * f0.y + f0.z * f0.z + f0.w * f0.w
                  + f1.x * f1.x + f1.y * f1.y + f1.z * f1.z + f1.w * f1.w;
#pragma unroll
        for (int m = 32; m; m >>= 1) nrm += __shfl_xor(nrm, m, 64);
        __shared__ float part[4];
        int lane = threadIdx.x & 63, w = threadIdx.x >> 6;
        if (lane == 0) part[w] = nrm;
        __syncthreads();
        if (threadIdx.x == 0)   cnorm[b2 * 2]     = part[0] + part[1];
        if (threadIdx.x == 128) cnorm[b2 * 2 + 1] = part[2] + part[3];
    } else {
        int i = (bid - 20480) * 256 + threadIdx.x;
        if (i < NSYM) { counts[i] = 0; cursors[i] = 0; }
        if (i == 0) { qcount[0] = 0; out_loss[0] = 0.0f; }
    }
}

// ---------------- bf16 MFMA screen (round-13 proven version) ----------------
__global__ __launch_bounds__(256, 4) void k_screen(
    const u16* __restrict__ Ah, const u16* __restrict__ Bh,
    const float* __restrict__ cnorm,
    float* __restrict__ candV, u16* __restrict__ candI)
{
    __shared__ __align__(16) unsigned char smA[16384];
    __shared__ __align__(16) unsigned char smB[16384];
    __shared__ float smv[128][2][2];
    __shared__ float smi[128][2];

    const int sblk = (blockIdx.x & 7) * 128 + (blockIdx.x >> 3);
    const int bx = sblk >> 2;
    const int by = sblk & 3;

    const int tid  = threadIdx.x;
    const int lane = tid & 63;
    const int w    = tid >> 6;
    const int wr   = w >> 1, wc = w & 1;
    const int row0 = bx * 128;
    const int sBase = w * 256;

    for (int cc = 0; cc < 16; ++cc) {
        const int chunk = by * 16 + cc;
        const int colBase = chunk * 128;

        f32x4 acc[4][4];
#pragma unroll
        for (int m = 0; m < 4; ++m)
#pragma unroll
            for (int n = 0; n < 4; ++n) acc[m][n] = (f32x4){0.f, 0.f, 0.f, 0.f};

        for (int ks = 0; ks < 16; ++ks) {
            const int kk0 = ks * 64;
            __syncthreads();
#pragma unroll
            for (int i = 0; i < 4; ++i) {
                int slot = sBase + i * 64 + lane;
                int r = slot >> 3;
                int c = (slot & 7) ^ (r & 7);
                const u16* ga = Ah + ((size_t)(row0 + r) * KDIM + kk0 + c * 8);
                GLOAD_LDS16(ga, smA + (size_t)(sBase + i * 64) * 16);
                const u16* gb = Bh + ((size_t)(colBase + r) * KDIM + kk0 + c * 8);
                GLOAD_LDS16(gb, smB + (size_t)(sBase + i * 64) * 16);
            }
            __syncthreads();
#pragma unroll
            for (int h = 0; h < 2; ++h) {
                short8 af[4], bfr[4];
#pragma unroll
                for (int m = 0; m < 4; ++m) {
                    int r = wr * 64 + m * 16 + (lane & 15);
                    int byte = r * 128 + h * 64 + (lane >> 4) * 16;
                    byte ^= (r & 7) << 4;
                    af[m] = *(const short8*)(smA + byte);
                }
#pragma unroll
                for (int n = 0; n < 4; ++n) {
                    int r = wc * 64 + n * 16 + (lane & 15);
                    int byte = r * 128 + h * 64 + (lane >> 4) * 16;
                    byte ^= (r & 7) << 4;
                    bfr[n] = *(const short8*)(smB + byte);
                }
#pragma unroll
                for (int m = 0; m < 4; ++m)
#pragma unroll
                    for (int n = 0; n < 4; ++n)
                        acc[m][n] = __builtin_amdgcn_mfma_f32_16x16x32_bf16(
                            af[m], bfr[n], acc[m][n], 0, 0, 0);
            }
        }

        float cn[4];
#pragma unroll
        for (int n = 0; n < 4; ++n)
            cn[n] = cnorm[colBase + wc * 64 + n * 16 + (lane & 15)];

#pragma unroll
        for (int m = 0; m < 4; ++m)
#pragma unroll
            for (int j = 0; j < 4; ++j) {
                int rowL = wr * 64 + m * 16 + (lane >> 4) * 4 + j;
                float v1 = INFINITY, v2 = INFINITY, i1v = 0.f;
#pragma unroll
                for (int n = 0; n < 4; ++n) {
                    float s = cn[n] - 2.0f * acc[m][n][j];
                    float ci = (float)(colBase + wc * 64 + n * 16 + (lane & 15));
                    if (s < v1) { v2 = v1; v1 = s; i1v = ci; }
                    else v2 = fminf(v2, s);
                }
#pragma unroll
                for (int msk = 1; msk < 16; msk <<= 1) {
                    float o1 = __shfl_xor(v1, msk, 16);
                    float oi = __shfl_xor(i1v, msk, 16);
                    float o2 = __shfl_xor(v2, msk, 16);
                    float n2 = fminf(fminf(v2, o2), fmaxf(v1, o1));
                    if (o1 < v1) { v1 = o1; i1v = oi; }
                    v2 = n2;
                }
                if ((lane & 15) == 0) {
                    smv[rowL][wc][0] = v1;  smv[rowL][wc][1] = v2;
                    smi[rowL][wc] = i1v;
                }
            }
        __syncthreads();
        {
            int half = tid >> 7;
            int row  = tid & 127;
            float v1 = smv[row][half][0], v2 = smv[row][half][1];
            float iv = smi[row][half];
            size_t tcol = (size_t)(row0 + row);
            int halfIdx = chunk * 2 + half;
            candV[(size_t)(halfIdx * 2 + 0) * M_TOK + tcol] = v1;
            candV[(size_t)(halfIdx * 2 + 1) * M_TOK + tcol] = v2;
            candI[(size_t)halfIdx * M_TOK + tcol]           = (u16)iv;
        }
    }
}

// ---------------- zero (fallback path only, after screen) ----------------
__global__ void k_zero(u32* __restrict__ counts, u32* __restrict__ cursors,
                       u32* __restrict__ qcount, float* __restrict__ out_loss) {
    int i = blockIdx.x * 256 + threadIdx.x;
    if (i < NSYM) { counts[i] = 0; cursors[i] = 0; }
    if (i == 0) { out_loss[0] = 0.0f; qcount[0] = 0; }
}

// ---------------- fp64 rescore helper ----------------
__device__ __forceinline__ void rescore(
    const float* __restrict__ codebook, const float* __restrict__ adjacency,
    const double* zreg, int prw, int col, int lane, double& bestS, int& bestI)
{
    const float* crow = codebook + (size_t)col * KDIM;
    double dot = 0.0, cn2 = 0.0;
#pragma unroll
    for (int j = 0; j < 16; ++j) {
        double c = (double)crow[lane + 64 * j];
        dot += c * zreg[j]; cn2 += c * c;
    }
#pragma unroll
    for (int m = 32; m; m >>= 1) {
        dot += __shfl_xor(dot, m, 64);
        cn2 += __shfl_xor(cn2, m, 64);
    }
    double a = (double)adjacency[(size_t)prw * NSYM + col];
    double sc = cn2 - 2.0 * dot - (double)GBS_F / (1.0 + exp(-a));
    if (sc < bestS || (sc == bestS && col < bestI)) { bestS = sc; bestI = col; }
}

// ---------------- select: inline singles; queue only scan-needing tokens ----------------
#define SEL_TOK 32
__global__ __launch_bounds__(256) void k_select(
    const float* __restrict__ zr, const float* __restrict__ zi,
    const int* __restrict__ prev,
    const float* __restrict__ codebook,
    const float* __restrict__ adjacency,
    const float* __restrict__ candV, const u16* __restrict__ candI,
    float* __restrict__ out_idx, u32* __restrict__ counts,
    u32* __restrict__ qcount, u32* __restrict__ queue)
{
    __shared__ float sv[256][SEL_TOK + 1];
    __shared__ u16   si[128][SEL_TOK + 2];
    const int tok0 = blockIdx.x * SEL_TOK;
    const int w = threadIdx.x >> 6, lane = threadIdx.x & 63;

    for (int idx = threadIdx.x; idx < 256 * SEL_TOK; idx += 256) {
        int e = idx >> 5, t = idx & (SEL_TOK - 1);
        sv[e][t] = candV[(size_t)e * M_TOK + tok0 + t];
    }
    for (int idx = threadIdx.x; idx < 128 * SEL_TOK; idx += 256) {
        int e = idx >> 5, t = idx & (SEL_TOK - 1);
        si[e][t] = candI[(size_t)e * M_TOK + tok0 + t];
    }
    __syncthreads();

    for (int tt = 0; tt < SEL_TOK / 4; ++tt) {
        const int t = w * (SEL_TOK / 4) + tt;
        const int tok = tok0 + t;
        float va1 = sv[4 * lane + 0][t];
        float va2 = sv[4 * lane + 1][t];
        float vb1 = sv[4 * lane + 2][t];
        float vb2 = sv[4 * lane + 3][t];
        int   ia  = (int)si[2 * lane + 0][t];
        int   ib  = (int)si[2 * lane + 1][t];

        float mm = fminf(va1, vb1);
#pragma unroll
        for (int m = 32; m; m >>= 1) mm = fminf(mm, __shfl_xor(mm, m, 64));
        const float thr = mm + WIN_F;

        unsigned long long m1a = __ballot(va1 <= thr);
        unsigned long long m1b = __ballot(vb1 <= thr);
        unsigned long long mh  = __ballot(va2 <= thr) | __ballot(vb2 <= thr);

        if (mh != 0) {
            if (lane == 0) { u32 q = atomicAdd(qcount, 1u); queue[q] = (u32)tok; }
        } else if (__popcll(m1a) + __popcll(m1b) == 1) {
            int bestI;
            if (m1a) { int c = __ffsll(m1a) - 1; bestI = __shfl(ia, c, 64); }
            else     { int c = __ffsll(m1b) - 1; bestI = __shfl(ib, c, 64); }
            if (lane == 0) {
                out_idx[tok] = (float)bestI;
                atomicAdd(&counts[bestI], 1u);
            }
        } else {
            double zreg[16];
#pragma unroll
            for (int j = 0; j < 8; ++j)
                zreg[j] = (double)zr[(size_t)tok * LAT + lane + 64 * j];
#pragma unroll
            for (int j = 0; j < 8; ++j)
                zreg[8 + j] = (double)zi[(size_t)tok * LAT + lane + 64 * j];
            const int prw = prev[tok];
            double bestS = DBL_MAX; int bestI = 0x7FFFFFFF;
            unsigned long long sa = m1a, sb = m1b;
            while (sa) { int c = __ffsll(sa) - 1; sa &= sa - 1;
                rescore(codebook, adjacency, zreg, prw, __shfl(ia, c, 64), lane, bestS, bestI); }
            while (sb) { int c = __ffsll(sb) - 1; sb &= sb - 1;
                rescore(codebook, adjacency, zreg, prw, __shfl(ib, c, 64), lane, bestS, bestI); }
            if (lane == 0) {
                out_idx[tok] = (float)bestI;
                atomicAdd(&counts[bestI], 1u);
            }
        }
    }
}

// ---------------- rescan: block per queued token, 4-wave-parallel candidate scan ----------------
#define MAXC 384
__global__ __launch_bounds__(256) void k_rescan(
    const float* __restrict__ zr, const float* __restrict__ zi,
    const int* __restrict__ prev,
    const float* __restrict__ codebook,
    const float* __restrict__ adjacency,
    const float* __restrict__ candV, const u16* __restrict__ candI,
    const u32* __restrict__ qcount, const u32* __restrict__ queue,
    float* __restrict__ out_idx, u32* __restrict__ counts)
{
    __shared__ double zd[KDIM];
    __shared__ float v1h[128], v2h[128];
    __shared__ u16   i1h[128];
    __shared__ int   collist[MAXC];
    __shared__ int   nsing_sh, nh_sh, scanall_sh;
    __shared__ int   halves[128];
    __shared__ double wsc[4];
    __shared__ int    wix[4];
    __shared__ float  mm_sh;

    const int tid = threadIdx.x;
    const int w = tid >> 6, lane = tid & 63;
    const u32 nq = qcount[0];

    for (u32 qi = blockIdx.x; qi < nq; qi += gridDim.x) {
        const int tok = (int)queue[qi];

        if (tid < 128) {
            v1h[tid] = candV[(size_t)(tid * 2 + 0) * M_TOK + tok];
            v2h[tid] = candV[(size_t)(tid * 2 + 1) * M_TOK + tok];
            i1h[tid] = candI[(size_t)tid * M_TOK + tok];
        }
        for (int k = tid; k < LAT; k += 256) {
            zd[k]       = (double)zr[(size_t)tok * LAT + k];
            zd[LAT + k] = (double)zi[(size_t)tok * LAT + k];
        }
        if (tid == 0) { nsing_sh = 0; nh_sh = 0; scanall_sh = 0; }
        __syncthreads();

        if (tid < 64) {
            float m = fminf(v1h[tid], v1h[tid + 64]);
#pragma unroll
            for (int s = 32; s; s >>= 1) m = fminf(m, __shfl_xor(m, s, 64));
            if (tid == 0) mm_sh = m;
        }
        __syncthreads();
        const float thr = mm_sh + WIN_F;

        if (tid < 128) {
            bool hs = (v2h[tid] <= thr);
            if (hs) { int p = atomicAdd(&nh_sh, 1); halves[p] = tid; }
            else if (v1h[tid] <= thr) { int p = atomicAdd(&nsing_sh, 1); collist[p] = (int)i1h[tid]; }
        }
        __syncthreads();
        int nsing = nsing_sh, nh = nh_sh;
        int nc = nsing + nh * 64;
        if (nc > MAXC) { if (tid == 0) scanall_sh = 1; }
        __syncthreads();
        if (!scanall_sh) {
            for (int h = 0; h < nh; ++h) {
                if (tid < 64) collist[nsing + h * 64 + tid] = halves[h] * 64 + tid;
            }
            nc = nsing + nh * 64;
        }
        __syncthreads();

        const int prw = prev[tok];
        double bestS = DBL_MAX; int bestI = 0x7FFFFFFF;
        const int total = scanall_sh ? NSYM : nc;
        for (int ci = w; ci < total; ci += 4) {
            int col = scanall_sh ? ci : collist[ci];
            const float* crow = codebook + (size_t)col * KDIM;
            double dot = 0.0, cn2 = 0.0;
#pragma unroll
            for (int j = 0; j < 16; ++j) {
                double c = (double)crow[lane + 64 * j];
                dot += c * zd[lane + 64 * j]; cn2 += c * c;
            }
#pragma unroll
            for (int s = 32; s; s >>= 1) {
                dot += __shfl_xor(dot, s, 64);
                cn2 += __shfl_xor(cn2, s, 64);
            }
            double a = (double)adjacency[(size_t)prw * NSYM + col];
            double sc = cn2 - 2.0 * dot - (double)GBS_F / (1.0 + exp(-a));
            if (sc < bestS || (sc == bestS && col < bestI)) { bestS = sc; bestI = col; }
        }
        if (lane == 0) { wsc[w] = bestS; wix[w] = bestI; }
        __syncthreads();
        if (tid == 0) {
            double bs = wsc[0]; int bi = wix[0];
#pragma unroll
            for (int q = 1; q < 4; ++q) {
                if (wsc[q] < bs || (wsc[q] == bs && wix[q] < bi)) { bs = wsc[q]; bi = wix[q]; }
            }
            out_idx[tok] = (float)bi;
            atomicAdd(&counts[bi], 1u);
        }
        __syncthreads();
    }
}

// ---------------- scan: offsets, new_cluster_size, n_total ----------------
__global__ __launch_bounds__(1024) void k_scan(
    const u32* __restrict__ counts, const float* __restrict__ cs_old,
    float* __restrict__ out_cs, u32* __restrict__ offsets,
    float* __restrict__ scal)
{
    const int tid = threadIdx.x;
    const int lane = tid & 63, w = tid >> 6;
    const int base = tid * 8;
    u32 c[8], pre[8], T = 0;
#pragma unroll
    for (int q = 0; q < 8; ++q) { c[q] = counts[base + q]; pre[q] = T; T += c[q]; }
    u32 inc = T;
#pragma unroll
    for (int d = 1; d < 64; d <<= 1) {
        u32 v = __shfl_up(inc, d, 64);
        if (lane >= d) inc += v;
    }
    __shared__ u32 wt[16];
    if (lane == 63) wt[w] = inc;
    __syncthreads();
    if (tid < 16) {
        u32 v = wt[tid];
#pragma unroll
        for (int d = 1; d < 16; d <<= 1) {
            u32 o = __shfl_up(v, d, 16);
            if (tid >= d) v += o;
        }
        wt[tid] = v;
    }
    __syncthreads();
    u32 ex = (w ? wt[w - 1] : 0) + inc - T;
#pragma unroll
    for (int q = 0; q < 8; ++q) offsets[base + q] = ex + pre[q];

    float nt = 0.0f;
#pragma unroll
    for (int q = 0; q < 8; ++q) {
        float ncs = cs_old[base + q] * DECAY_F + OMD_F * (float)c[q];
        out_cs[base + q] = ncs;
        nt += ncs;
    }
#pragma unroll
    for (int m = 32; m; m >>= 1) nt += __shfl_xor(nt, m, 64);
    __shared__ float red[16];
    if (lane == 0) red[w] = nt;
    __syncthreads();
    if (tid == 0) {
        float s = 0.0f;
#pragma unroll
        for (int i = 0; i < 16; ++i) s += red[i];
        scal[0] = s;
        scal[1] = s + (float)NSYM * EPS_F;
    }
}

// ---------------- place: token lists per symbol ----------------
__global__ void k_place(const float* __restrict__ idxf, const u32* __restrict__ offsets,
                        u32* __restrict__ cursors, u32* __restrict__ list) {
    int t = blockIdx.x * 256 + threadIdx.x;
    int s = (int)idxf[t];
    u32 slot = atomicAdd(&cursors[s], 1u);
    list[offsets[s] + slot] = (u32)t;
}

// ---------------- emit FUSED with zq, 2-token-parallel (ws path) ----------------
__global__ __launch_bounds__(256) void k_emit_fused(
    const float* __restrict__ zr, const float* __restrict__ zi,
    const float* __restrict__ codebook, const float* __restrict__ embed_avg,
    const u32* __restrict__ counts, const u32* __restrict__ offsets,
    const u32* __restrict__ list, const float* __restrict__ out_cs,
    const float* __restrict__ scal,
    float* __restrict__ out_ea, float* __restrict__ out_cb,
    float* __restrict__ out_zc, float* __restrict__ out_loss, int interleaved)
{
    const int s = blockIdx.x;
    const u32 cnt = counts[s], off = offsets[s];
    const int g = threadIdx.x >> 7;          // token group 0/1
    const int j = (threadIdx.x & 127) * 4;   // column quad
    float4 cbr = *(const float4*)&codebook[(size_t)s * KDIM + j];
    float4 cbi = *(const float4*)&codebook[(size_t)s * KDIM + LAT + j];
    float ar0 = 0.f, ar1 = 0.f, ar2 = 0.f, ar3 = 0.f;
    float ai0 = 0.f, ai1 = 0.f, ai2 = 0.f, ai3 = 0.f;
    float lsum = 0.f;
    for (u32 n = g; n < cnt; n += 2) {
        int t = (int)list[off + n];
        float4 z0 = *(const float4*)&zr[(size_t)t * LAT + j];
        float4 z1 = *(const float4*)&zi[(size_t)t * LAT + j];
        ar0 += z0.x; ar1 += z0.y; ar2 += z0.z; ar3 += z0.w;
        ai0 += z1.x; ai1 += z1.y; ai2 += z1.z; ai3 += z1.w;
        if (interleaved) {
            float2* dst = (float2*)out_zc + (size_t)t * LAT + j;
            dst[0] = make_float2(cbr.x, cbi.x); dst[1] = make_float2(cbr.y, cbi.y);
            dst[2] = make_float2(cbr.z, cbi.z); dst[3] = make_float2(cbr.w, cbi.w);
        } else {
            *(float4*)&out_zc[(size_t)t * LAT + j] = cbr;
        }
        float d;
        d = cbr.x - z0.x; lsum += d * d;  d = cbr.y - z0.y; lsum += d * d;
        d = cbr.z - z0.z; lsum += d * d;  d = cbr.w - z0.w; lsum += d * d;
        d = cbi.x - z1.x; lsum += d * d;  d = cbi.y - z1.y; lsum += d * d;
        d = cbi.z - z1.z; lsum += d * d;  d = cbi.w - z1.w; lsum += d * d;
    }
    __shared__ float comb[128][8];
    if (g == 1) {
        int r = threadIdx.x & 127;
        comb[r][0] = ar0; comb[r][1] = ar1; comb[r][2] = ar2; comb[r][3] = ar3;
        comb[r][4] = ai0; comb[r][5] = ai1; comb[r][6] = ai2; comb[r][7] = ai3;
    }
    __syncthreads();
    if (g == 0) {
        int r = threadIdx.x;
        ar0 += comb[r][0]; ar1 += comb[r][1]; ar2 += comb[r][2]; ar3 += comb[r][3];
        ai0 += comb[r][4]; ai1 += comb[r][5]; ai2 += comb[r][6]; ai3 += comb[r][7];
        float4 ea0 = *(const float4*)&embed_avg[(size_t)s * KDIM + j];
        float4 ea1 = *(const float4*)&embed_avg[(size_t)s * KDIM + LAT + j];
        float4 ner = make_float4(ea0.x * DECAY_F + ar0 * OMD_F, ea0.y * DECAY_F + ar1 * OMD_F,
                                 ea0.z * DECAY_F + ar2 * OMD_F, ea0.w * DECAY_F + ar3 * OMD_F);
        float4 nei = make_float4(ea1.x * DECAY_F + ai0 * OMD_F, ea1.y * DECAY_F + ai1 * OMD_F,
                                 ea1.z * DECAY_F + ai2 * OMD_F, ea1.w * DECAY_F + ai3 * OMD_F);
        *(float4*)&out_ea[(size_t)s * KDIM + j]       = ner;
        *(float4*)&out_ea[(size_t)s * KDIM + LAT + j] = nei;
        float ntot = scal[0], denom = scal[1];
        float cs = (out_cs[s] + EPS_F) / denom * ntot;
        float inv = 1.0f / cs;
        *(float4*)&out_cb[(size_t)s * KDIM + j] =
            make_float4(ner.x * inv, ner.y * inv, ner.z * inv, ner.w * inv);
        *(float4*)&out_cb[(size_t)s * KDIM + LAT + j] =
            make_float4(nei.x * inv, nei.y * inv, nei.z * inv, nei.w * inv);
    }
#pragma unroll
    for (int m = 32; m; m >>= 1) lsum += __shfl_xor(lsum, m, 64);
    __shared__ float red[4];
    int wv = threadIdx.x >> 6, lane = threadIdx.x & 63;
    if (lane == 0) red[wv] = lsum;
    __syncthreads();
    if (threadIdx.x == 0)
        atomicAdd(out_loss, (red[0] + red[1] + red[2] + red[3]) * LOSS_SCALE);
}

// ---------------- emit (fallback, unfused) ----------------
__global__ __launch_bounds__(256) void k_emit(
    const float* __restrict__ zr, const float* __restrict__ zi,
    const float* __restrict__ embed_avg,
    const u32* __restrict__ counts, const u32* __restrict__ offsets,
    const u32* __restrict__ list, const float* __restrict__ out_cs,
    const float* __restrict__ scal,
    float* __restrict__ out_ea, float* __restrict__ out_cb)
{
    const int s = blockIdx.x;
    const u32 cnt = counts[s], off = offsets[s];
    const int j = threadIdx.x * 4;
    float a0 = 0.f, a1 = 0.f, a2 = 0.f, a3 = 0.f;
    for (u32 n = 0; n < cnt; ++n) {
        int t = (int)list[off + n];
        const float* src = (j < 512) ? zr + (size_t)t * 512 + j
                                     : zi + (size_t)t * 512 + (j - 512);
        float4 v = *(const float4*)src;
        a0 += v.x; a1 += v.y; a2 += v.z; a3 += v.w;
    }
    float4 ea = *(const float4*)&embed_avg[(size_t)s * KDIM + j];
    float4 nea = make_float4(ea.x * DECAY_F + a0 * OMD_F,
                             ea.y * DECAY_F + a1 * OMD_F,
                             ea.z * DECAY_F + a2 * OMD_F,
                             ea.w * DECAY_F + a3 * OMD_F);
    *(float4*)&out_ea[(size_t)s * KDIM + j] = nea;
    float ntot = scal[0], denom = scal[1];
    float cs = (out_cs[s] + EPS_F) / denom * ntot;
    float inv = 1.0f / cs;
    *(float4*)&out_cb[(size_t)s * KDIM + j] =
        make_float4(nea.x * inv, nea.y * inv, nea.z * inv, nea.w * inv);
}

// ---------------- zq (fallback, unfused; loss pre-scaled) ----------------
__global__ __launch_bounds__(256) void k_zq(
    const float* __restrict__ zr, const float* __restrict__ zi,
    const float* __restrict__ codebook, const float* __restrict__ idxf,
    float* __restrict__ out_zc, float* __restrict__ out_loss, int interleaved)
{
    const int w = threadIdx.x >> 6, lane = threadIdx.x & 63;
    const int tok = blockIdx.x * 4 + w;
    const int mi = (int)idxf[tok];
    const int j0 = lane * 8;
    float4 re0 = *(const float4*)&codebook[(size_t)mi * KDIM + j0];
    float4 re1 = *(const float4*)&codebook[(size_t)mi * KDIM + j0 + 4];
    float4 im0 = *(const float4*)&codebook[(size_t)mi * KDIM + LAT + j0];
    float4 im1 = *(const float4*)&codebook[(size_t)mi * KDIM + LAT + j0 + 4];
    float4 zr0 = *(const float4*)&zr[(size_t)tok * LAT + j0];
    float4 zr1 = *(const float4*)&zr[(size_t)tok * LAT + j0 + 4];
    float4 zi0 = *(const float4*)&zi[(size_t)tok * LAT + j0];
    float4 zi1 = *(const float4*)&zi[(size_t)tok * LAT + j0 + 4];
    if (interleaved) {
        float2* dst = (float2*)out_zc + (size_t)tok * LAT + j0;
        dst[0] = make_float2(re0.x, im0.x); dst[1] = make_float2(re0.y, im0.y);
        dst[2] = make_float2(re0.z, im0.z); dst[3] = make_float2(re0.w, im0.w);
        dst[4] = make_float2(re1.x, im1.x); dst[5] = make_float2(re1.y, im1.y);
        dst[6] = make_float2(re1.z, im1.z); dst[7] = make_float2(re1.w, im1.w);
    } else {
        *(float4*)&out_zc[(size_t)tok * LAT + j0]     = re0;
        *(float4*)&out_zc[(size_t)tok * LAT + j0 + 4] = re1;
    }
    float l = 0.f;
    l += (re0.x-zr0.x)*(re0.x-zr0.x) + (re0.y-zr0.y)*(re0.y-zr0.y)
       + (re0.z-zr0.z)*(re0.z-zr0.z) + (re0.w-zr0.w)*(re0.w-zr0.w);
    l += (re1.x-zr1.x)*(re1.x-zr1.x) + (re1.y-zr1.y)*(re1.y-zr1.y)
       + (re1.z-zr1.z)*(re1.z-zr1.z) + (re1.w-zr1.w)*(re1.w-zr1.w);
    l += (im0.x-zi0.x)*(im0.x-zi0.x) + (im0.y-zi0.y)*(im0.y-zi0.y)
       + (im0.z-zi0.z)*(im0.z-zi0.z) + (im0.w-zi0.w)*(im0.w-zi0.w);
    l += (im1.x-zi1.x)*(im1.x-zi1.x) + (im1.y-zi1.y)*(im1.y-zi1.y)
       + (im1.z-zi1.z)*(im1.z-zi1.z) + (im1.w-zi1.w)*(im1.w-zi1.w);
#pragma unroll
    for (int m = 32; m; m >>= 1) l += __shfl_xor(l, m, 64);
    if (lane == 0) atomicAdd(out_loss, l * LOSS_SCALE);
}

extern "C" void kernel_launch(void* const* d_in, const int* in_sizes, int n_in,
                              void* d_out, int out_size, void* d_ws, size_t ws_size,
                              hipStream_t stream) {
    const float* z_real     = (const float*)d_in[0];
    const float* z_imag     = (const float*)d_in[1];
    const int*   prev_idx   = (const int*)d_in[2];
    const float* codebook   = (const float*)d_in[3];
    const float* cluster_sz = (const float*)d_in[4];
    const float* embed_avg  = (const float*)d_in[5];
    const float* adjacency  = (const float*)d_in[6];

    float* out = (float*)d_out;

    const size_t REST = 1 + (size_t)M_TOK + (size_t)NSYM * KDIM + NSYM
                      + (size_t)NSYM * KDIM;               // 16,818,177
    size_t zc_n = (size_t)out_size - REST;
    const size_t n_z = (size_t)M_TOK * LAT;
    int interleaved = (zc_n >= 2 * n_z) ? 1 : 0;

    float* out_zc   = out;
    float* out_loss = out + zc_n;
    float* out_idx  = out + zc_n + 1;
    float* out_cb   = out + zc_n + 1 + M_TOK;
    float* out_cs   = out_cb + (size_t)NSYM * KDIM;
    float* out_ea   = out_cs + NSYM;

    // phase-1 scratch (screen inputs), carved from output regions:
    u16*   A_hi  = (u16*)out_zc;                       // 67.1 MB (zc region)
    u16*   B_hi  = (u16*)out_cb;                       // 16.8 MB (cb region)
    float* cnorm = out_cb + 4194304;                   // 32 KB after B_hi
    float* candV = out_ea;                             // 33.5 MB [256][M]
    u16*   candI = (u16*)(out_cb + 4202496);           // 8.4 MB  [128][M]

    // phase-2 scratch: prefer d_ws (enables fused emit+zq); fallback to zc region
    const size_t WS_NEED = (size_t)(NSYM * 3 + M_TOK * 2 + 8) * 4;  // ~360 KB
    int use_ws = (ws_size >= WS_NEED) ? 1 : 0;
    u32 *counts, *cursors, *offsets, *list, *qcount, *queue;
    float* scal;
    if (use_ws) {
        u32* wsp = (u32*)d_ws;
        counts  = wsp;             cursors = counts + NSYM;
        offsets = cursors + NSYM;  list    = offsets + NSYM;
        queue   = list + M_TOK;
        scal    = (float*)(queue + M_TOK);
        qcount  = (u32*)(scal + 2);
    } else {
        counts  = (u32*)out_zc;    cursors = counts + NSYM;
        offsets = cursors + NSYM;  list    = offsets + NSYM;
        scal    = (float*)(list + M_TOK);
        qcount  = (u32*)(scal + 2);
        queue   = qcount + 1;
    }

    k_conv<<<use_ws ? 20512 : 20480, 256, 0, stream>>>(z_real, z_imag, codebook,
                                                       A_hi, B_hi, cnorm,
                                                       counts, cursors, qcount,
                                                       out_loss);
    k_screen<<<1024, 256, 0, stream>>>(A_hi, B_hi, cnorm, candV, candI);
    if (!use_ws)
        k_zero<<<32, 256, 0, stream>>>(counts, cursors, qcount, out_loss);
    k_select<<<M_TOK / SEL_TOK, 256, 0, stream>>>(z_real, z_imag, prev_idx,
                                                  codebook, adjacency,
                                                  candV, candI, out_idx, counts,
                                                  qcount, queue);
    k_rescan<<<256, 256, 0, stream>>>(z_real, z_imag, prev_idx, codebook,
                                      adjacency, candV, candI,
                                      qcount, queue, out_idx, counts);
    k_scan<<<1, 1024, 0, stream>>>(counts, cluster_sz, out_cs, offsets, scal);
    k_place<<<M_TOK / 256, 256, 0, stream>>>(out_idx, offsets, cursors, list);
    if (use_ws) {
        k_emit_fused<<<NSYM, 256, 0, stream>>>(z_real, z_imag, codebook, embed_avg,
                                               counts, offsets, list, out_cs, scal,
                                               out_ea, out_cb, out_zc, out_loss,
                                               interleaved);
    } else {
        k_emit<<<NSYM, 256, 0, stream>>>(z_real, z_imag, embed_avg, counts, offsets,
                                         list, out_cs, scal, out_ea, out_cb);
        k_zq<<<M_TOK / 4, 256, 0, stream>>>(z_real, z_imag, codebook, out_idx,
                                            out_zc, out_loss, interleaved);
    }
}